// Round 20
// baseline (237.940 us; speedup 1.0000x reference)
//
#include <hip/hip_runtime.h>
#include <stdint.h>

// HamiltonianFlow: x [256, 8, 32, 2] (q,p); H = 0.5*sum(p^2) + MLP(q).
// dq/dt = p, dp/dt = -W u(z), z = W^T q + b1, u = (1-tanh^2(z)).*W2.
// 100 RK4 steps, z-space iteration with M = W^T W (R15-R19 verified):
//   z2 = z1+hdt*P; z3 = z1+hdt*P-hdt^2*Y1; z4 = z1+dt*P-dt*hdt*Y2; Y_i = M u_i
//   z1' = z1+dt*P-dt*dt6*(Y1+Y2+Y3);  P' = P-dt6*(Y1+2Y2+2Y3+Y4)
// Phase A: u1,u2 -> {Y1,Y2}; phase B: u3,u4 -> {Y3,Y4}. 1 barrier/phase.
//
// R20: (a) 4 WAVES x 4 TILES: R19's wall was 64 broadcast ds_read_b128/CU/
// phase (~768 cyc serial on the shared LDS pipe) -- A-frags are tile-
// independent, so 4 tiles/wave -> 32 reads/CU (~384 cyc), each feeding 8
// MFMAs. MFMA issue/SIMD unchanged (32 x 19.4 = 620). 1 wave/SIMD exposes
// the ~250-cyc tanh tail (risk, see R14) but wins ~400 cyc/phase on LDS.
// (b) TRANSPOSED W staging: wldsT[c*WS+r] = W[r][c], so wF and the M-build
// aM gathers are contiguous b128 (was 1024 scalar ds_read_u16/lane ~= half
// the prologue); staging via coalesced global column reads + b128 writes.
// Packed-pair A rows (R18): rows m%4==0 <- vec1, m%4==1 <- vec2; ubuf row
// stride US=288 f16 (576B == 64 mod 128: bank-split, conflict-free);
// results in-lane: Y_vec1 = C[0], Y_vec2 = C[1]. AGPR-direct wM ("a").
// Wave w owns comps ci = 64w+16i+s, i=0..3 (quads dup).
// Reconstruction (R15): sp=u1+2u2+2u3+u4, sq=u1+u2+u3; S1=sum sp_n,
// S23=sum (99-n)sp_n+sq_n; p_T=p0-dt6*W*S1, q_T=q0+dt*100*p0-dt*dt6*W*S23.
// FULL unroll on every reg-array access (R4: dynamic index => scratch).
// Numerics: f16 storage (W, M, u, S), fp32 MFMA accum + fp32 z1/P state.

typedef _Float16 v8h __attribute__((ext_vector_type(8)));
typedef float v4f __attribute__((ext_vector_type(4)));

#define NSTEPS 100
#define WS 264    // wldsT row stride (f16): row = one W-COLUMN, 16B-aligned
#define US 288    // ubuf row stride, f16 (576 B == 64 mod 128: bank-split)

// D(+=C) in VGPRs, A (packed-vector frag) in VGPRs, B (M-frag) from AGPRs.
#define MFMA_AV(C, A, B) \
    asm("v_mfma_f32_16x16x32_f16 %0, %1, %2, %0" : "+v"(C) : "v"(A), "a"(B))

__global__ __launch_bounds__(256, 1)
void ham_kernel(const float* __restrict__ x0, const float* __restrict__ W1,
                const float* __restrict__ b1, const float* __restrict__ W2,
                float* __restrict__ out)
{
    __shared__ __align__(16)  _Float16 wldsT[256 * WS];  // 135168 B: W^T (f16)
    __shared__ __align__(16)  float    mscr[16 * 320];   // 20480 B: M scratch
    __shared__ __align__(128) _Float16 ubuf[4 * US];     // 2304 B: 4 vec rows

    const int t = threadIdx.x;
    const int w = t >> 6;          // wave 0..3: owns tiles {4w..4w+3}
    const int l = t & 63;
    const int quad = l >> 4;       // K-subgroup
    const int s = l & 15;          // owned column / A-row
    const int blk = blockIdx.x;
    const int sel = ((s & 3) == 1) ? US : 0;   // A-row m%4==1 -> 2nd vector
    const int cbase = 64 * w + s;  // comp i: cbase + 16*i

    // ---- stage W^T -> LDS f16: wldsT[c][r] = W[r][c] ----
    // thread t handles column c = t; global reads coalesced over lanes.
    {
        const int c = t;
        #pragma unroll 1
        for (int r0 = 0; r0 < 256; r0 += 8) {
            v8h h;
            #pragma unroll
            for (int j = 0; j < 8; ++j)
                h[j] = (_Float16)W1[(r0 + j) * 256 + c];
            *(v8h*)(wldsT + c * WS + r0) = h;   // b128, one-time 8-way ok
        }
    }
    __syncthreads();

    // ---- wF: W^T-frag (B-op), 4 tiles, contiguous b128 from wldsT ----
    // wF[i][kk][j] = W[32kk+8quad+j][ci] = wldsT[ci*WS + 32kk+8quad+j]
    v8h wF[4][8];
    #pragma unroll
    for (int i = 0; i < 4; ++i)
        #pragma unroll
        for (int kk = 0; kk < 8; ++kk)
            wF[i][kk] = *(const v8h*)(wldsT + (cbase + 16 * i) * WS
                                             + 32 * kk + 8 * quad);

    // ---- build M = W^T W col-block frags wM[i] (B-op: M[k][ci]) ----
    // tile kb: D[m][n] = M[16kb+m][64w+16i+n]; aM contiguous b128 (shared).
    v8h wM[4][8];
    #pragma unroll
    for (int kb = 0; kb < 16; ++kb) {
        v8h aM[8];   // A[m=s][k=8quad+j] = wldsT[(16kb+s)*WS + 32kk+8quad+j]
        #pragma unroll
        for (int kk = 0; kk < 8; ++kk)
            aM[kk] = *(const v8h*)(wldsT + (16 * kb + s) * WS
                                          + 32 * kk + 8 * quad);
        v4f D0 = {0.f,0.f,0.f,0.f}, D1 = {0.f,0.f,0.f,0.f};
        v4f D2 = {0.f,0.f,0.f,0.f}, D3 = {0.f,0.f,0.f,0.f};
        #pragma unroll
        for (int kk = 0; kk < 8; ++kk) {
            D0 = __builtin_amdgcn_mfma_f32_16x16x32_f16(aM[kk], wF[0][kk], D0, 0, 0, 0);
            D1 = __builtin_amdgcn_mfma_f32_16x16x32_f16(aM[kk], wF[1][kk], D1, 0, 0, 0);
            D2 = __builtin_amdgcn_mfma_f32_16x16x32_f16(aM[kk], wF[2][kk], D2, 0, 0, 0);
            D3 = __builtin_amdgcn_mfma_f32_16x16x32_f16(aM[kk], wF[3][kk], D3, 0, 0, 0);
        }
        float* scr = mscr + (w * 4) * 320;
        *(v4f*)(scr + 0 * 320 + s * 20 + 4 * quad) = D0;
        *(v4f*)(scr + 1 * 320 + s * 20 + 4 * quad) = D1;
        *(v4f*)(scr + 2 * 320 + s * 20 + 4 * quad) = D2;
        *(v4f*)(scr + 3 * 320 + s * 20 + 4 * quad) = D3;
        asm volatile("s_waitcnt lgkmcnt(0)" ::: "memory");  // in-wave x-lane
        if ((quad >> 1) == (kb & 1)) {
            #pragma unroll
            for (int j = 0; j < 8; ++j) {
                wM[0][kb >> 1][j] = (_Float16)scr[0 * 320 + s * 20 + 8 * (quad & 1) + j];
                wM[1][kb >> 1][j] = (_Float16)scr[1 * 320 + s * 20 + 8 * (quad & 1) + j];
                wM[2][kb >> 1][j] = (_Float16)scr[2 * 320 + s * 20 + 8 * (quad & 1) + j];
                wM[3][kb >> 1][j] = (_Float16)scr[3 * 320 + s * 20 + 8 * (quad & 1) + j];
            }
        }
        asm volatile("s_waitcnt lgkmcnt(0)" ::: "memory");
    }

    float b1r[4], w2r[4], q0o[4], p0o[4];
    #pragma unroll
    for (int i = 0; i < 4; ++i) {
        const int ci = cbase + 16 * i;
        b1r[i] = b1[ci];
        w2r[i] = W2[ci];
        float2 qp = ((const float2*)(x0 + (size_t)blk * 512))[ci];
        q0o[i] = qp.x; p0o[i] = qp.y;
        if (quad == 0) {
            ubuf[ci] = (_Float16)qp.x;
            ubuf[US + ci] = (_Float16)qp.y;
        }
    }
    __syncthreads();

    // ---- prologue: rows {q0,p0} -> z1 = W^T q0 + b1 (C[0]), P (C[1]) ----
    float z1[4], P[4];
    {
        const _Float16* ab = ubuf + sel + 8 * quad;
        v4f Ca[4], Cb[4];
        #pragma unroll
        for (int i = 0; i < 4; ++i) { Ca[i] = (v4f){0.f,0.f,0.f,0.f}; Cb[i] = Ca[i]; }
        #pragma unroll
        for (int kk = 0; kk < 8; kk += 2) {
            v8h a0 = *(const v8h*)(ab + 32 * kk);
            v8h a1 = *(const v8h*)(ab + 32 * (kk + 1));
            #pragma unroll
            for (int i = 0; i < 4; ++i) {
                Ca[i] = __builtin_amdgcn_mfma_f32_16x16x32_f16(a0, wF[i][kk], Ca[i], 0, 0, 0);
                Cb[i] = __builtin_amdgcn_mfma_f32_16x16x32_f16(a1, wF[i][kk + 1], Cb[i], 0, 0, 0);
            }
        }
        #pragma unroll
        for (int i = 0; i < 4; ++i) {
            z1[i] = Ca[i][0] + Cb[i][0] + b1r[i];
            P[i]  = Ca[i][1] + Cb[i][1];
        }
    }
    __syncthreads();   // protect ubuf before loop overwrites

    const float dt = 0.01f, hdt = 0.005f, dt6 = 0.01f / 6.f;
    const float dtdt6 = dt * dt6, hdt2 = hdt * hdt, dthdt = dt * hdt;

    float S1[4] = {0.f,0.f,0.f,0.f}, S23[4] = {0.f,0.f,0.f,0.f};
    float cn = 99.f;

    #pragma unroll 1
    for (int n = 0; n < NSTEPS; ++n) {
        // ======== phase A: u1,u2 (4 comps) -> packed MFMA -> Y1,Y2 ========
        float u1[4], u2[4];
        #pragma unroll
        for (int i = 0; i < 4; ++i) {
            float z2 = z1[i] + hdt * P[i];
            float e1 = __expf(2.f * z1[i]), e2 = __expf(2.f * z2);
            float h1 = 1.f - 2.f / (e1 + 1.f), h2 = 1.f - 2.f / (e2 + 1.f);
            u1[i] = (1.f - h1 * h1) * w2r[i];
            u2[i] = (1.f - h2 * h2) * w2r[i];
            if (quad == 0) {
                ubuf[cbase + 16 * i] = (_Float16)u1[i];
                ubuf[US + cbase + 16 * i] = (_Float16)u2[i];
            }
        }
        __syncthreads();

        float Y1[4], Y2[4];
        {
            const _Float16* ab = ubuf + sel + 8 * quad;
            v8h au[8];
            #pragma unroll
            for (int kk = 0; kk < 8; ++kk)
                au[kk] = *(const v8h*)(ab + 32 * kk);
            v4f Ca[4], Cb[4];
            #pragma unroll
            for (int i = 0; i < 4; ++i) { Ca[i] = (v4f){0.f,0.f,0.f,0.f}; Cb[i] = Ca[i]; }
            #pragma unroll
            for (int kk = 0; kk < 8; kk += 2)
                #pragma unroll
                for (int i = 0; i < 4; ++i) {
                    MFMA_AV(Ca[i], au[kk], wM[i][kk]);
                    MFMA_AV(Cb[i], au[kk + 1], wM[i][kk + 1]);
                }
            #pragma unroll
            for (int i = 0; i < 4; ++i) {
                Y1[i] = Ca[i][0] + Cb[i][0];
                Y2[i] = Ca[i][1] + Cb[i][1];
            }
        }

        // ======== phase B: u3,u4 -> packed MFMA -> Y3,Y4 ========
        float u3[4], u4[4];
        #pragma unroll
        for (int i = 0; i < 4; ++i) {
            float z3 = z1[i] + hdt * P[i] - hdt2 * Y1[i];
            float z4 = z1[i] + dt * P[i] - dthdt * Y2[i];
            float e3 = __expf(2.f * z3), e4 = __expf(2.f * z4);
            float h3 = 1.f - 2.f / (e3 + 1.f), h4 = 1.f - 2.f / (e4 + 1.f);
            u3[i] = (1.f - h3 * h3) * w2r[i];
            u4[i] = (1.f - h4 * h4) * w2r[i];
            if (quad == 0) {
                ubuf[2 * US + cbase + 16 * i] = (_Float16)u3[i];
                ubuf[3 * US + cbase + 16 * i] = (_Float16)u4[i];
            }
        }
        __syncthreads();

        float Y3[4], Y4[4];
        {
            const _Float16* ab = ubuf + 2 * US + sel + 8 * quad;
            v8h au[8];
            #pragma unroll
            for (int kk = 0; kk < 8; ++kk)
                au[kk] = *(const v8h*)(ab + 32 * kk);
            v4f Ca[4], Cb[4];
            #pragma unroll
            for (int i = 0; i < 4; ++i) { Ca[i] = (v4f){0.f,0.f,0.f,0.f}; Cb[i] = Ca[i]; }
            #pragma unroll
            for (int kk = 0; kk < 8; kk += 2)
                #pragma unroll
                for (int i = 0; i < 4; ++i) {
                    MFMA_AV(Ca[i], au[kk], wM[i][kk]);
                    MFMA_AV(Cb[i], au[kk + 1], wM[i][kk + 1]);
                }
            #pragma unroll
            for (int i = 0; i < 4; ++i) {
                Y3[i] = Ca[i][0] + Cb[i][0];
                Y4[i] = Ca[i][1] + Cb[i][1];
            }
        }

        // ======== step update (z1 uses OLD P) ========
        #pragma unroll
        for (int i = 0; i < 4; ++i) {
            z1[i] = z1[i] + dt * P[i] - dtdt6 * (Y1[i] + Y2[i] + Y3[i]);
            P[i]  = P[i] - dt6 * (Y1[i] + 2.f * Y2[i] + 2.f * Y3[i] + Y4[i]);
            float sp = u1[i] + 2.f * u2[i] + 2.f * u3[i] + u4[i];
            float sq = u1[i] + u2[i] + u3[i];
            S1[i] += sp; S23[i] += cn * sp + sq;
        }
        cn -= 1.f;
    }

    // ---- epilogue: rows {S1,S23}: p_T = p0 - dt6*W*S1;
    //      q_T = q0 + dt*100*p0 - dt*dt6*W*S23 ----
    __syncthreads();   // all waves done reading ubuf before rewrite
    #pragma unroll
    for (int i = 0; i < 4; ++i)
        if (quad == 0) {
            ubuf[cbase + 16 * i] = (_Float16)S1[i];
            ubuf[US + cbase + 16 * i] = (_Float16)S23[i];
        }
    __syncthreads();
    // wBt[i][kk][j] = W[ci][32kk+8quad+j] = wldsT[(32kk+8quad+j)*WS + ci]
    v8h wBt[4][8];
    #pragma unroll
    for (int i = 0; i < 4; ++i)
        #pragma unroll
        for (int kk = 0; kk < 8; ++kk)
            #pragma unroll
            for (int j = 0; j < 8; ++j)
                wBt[i][kk][j] = wldsT[(32 * kk + 8 * quad + j) * WS + cbase + 16 * i];
    {
        const _Float16* ab = ubuf + sel + 8 * quad;
        v4f Ca[4], Cb[4];
        #pragma unroll
        for (int i = 0; i < 4; ++i) { Ca[i] = (v4f){0.f,0.f,0.f,0.f}; Cb[i] = Ca[i]; }
        #pragma unroll
        for (int kk = 0; kk < 8; kk += 2)
            #pragma unroll
            for (int i = 0; i < 4; ++i) {
                Ca[i] = __builtin_amdgcn_mfma_f32_16x16x32_f16(
                            *(const v8h*)(ab + 32 * kk), wBt[i][kk], Ca[i], 0, 0, 0);
                Cb[i] = __builtin_amdgcn_mfma_f32_16x16x32_f16(
                            *(const v8h*)(ab + 32 * (kk + 1)), wBt[i][kk + 1], Cb[i], 0, 0, 0);
            }
        #pragma unroll
        for (int i = 0; i < 4; ++i) {
            float D1v = Ca[i][0] + Cb[i][0];
            float D2v = Ca[i][1] + Cb[i][1];
            float pT = p0o[i] - dt6 * D1v;
            float qT = q0o[i] + dt * (float)NSTEPS * p0o[i] - dtdt6 * D2v;
            if (quad == 0)
                ((float2*)(out + (size_t)blk * 512))[cbase + 16 * i] =
                    make_float2(qT, pT);
        }
    }
}

extern "C" void kernel_launch(void* const* d_in, const int* in_sizes, int n_in,
                              void* d_out, int out_size, void* d_ws, size_t ws_size,
                              hipStream_t stream) {
    const float* x0 = (const float*)d_in[0];
    const float* W1 = (const float*)d_in[1];
    const float* b1 = (const float*)d_in[2];
    const float* W2 = (const float*)d_in[3];
    // d_in[4] = b2: constant offset, no effect on the gradient/dynamics.
    float* out = (float*)d_out;
    hipLaunchKernelGGL(ham_kernel, dim3(256), dim3(256), 0, stream,
                       x0, W1, b1, W2, out);
}

// Round 21
// 213.557 us; speedup vs baseline: 1.1142x; 1.1142x over previous
//
#include <hip/hip_runtime.h>
#include <stdint.h>

// HamiltonianFlow: x [256, 8, 32, 2] (q,p); H = 0.5*sum(p^2) + MLP(q).
// dq/dt = p, dp/dt = -W u(z), z = W^T q + b1, u = (1-tanh^2(z)).*W2.
// 100 RK4 steps, z-space iteration with M = W^T W (R15-R20 verified):
//   z2 = z1+hdt*P; z3 = z1+hdt*P-hdt^2*Y1; z4 = z1+dt*P-dt*hdt*Y2; Y_i = M u_i
//   z1' = z1+dt*P-dt*dt6*(Y1+Y2+Y3);  P' = P-dt6*(Y1+2Y2+2Y3+Y4)
// Phase A: u1,u2 -> {Y1,Y2}; phase B: u3,u4 -> {Y3,Y4}. 1 barrier/phase,
// 200 phases total (RK4 dependency minimum; grid pinned 256 blocks = 1/CU).
//
// R21 = R19 loop (8 waves x 2 tiles, 2 waves/SIMD -- best steady 188us;
// 2-wave overlap covers read/tail latency, R14/R20 showed 1 wave/SIMD
// exposes it) + R20 staging (TRANSPOSED W^T in LDS: wldsT[c*WS+r] = W[r][c],
// so wF / M-build aM are contiguous ds_read_b128 instead of 1024 scalar
// ds_read_u16 per lane -- prologue ~20us cheaper, conflicts 5.1e6->2.4e6).
// Wave w owns comps c0=32w+s (tile 2w), c1=32w+16+s (tile 2w+1); quads dup.
// Packed-pair A rows (R18): rows m%4==0 <- vec1, m%4==1 <- vec2; ubuf row
// stride US=288 f16 (576B == 64 mod 128: bank-split, conflict-free);
// results in-lane: Y_vec1 = Cs[0], Y_vec2 = Cs[1]. AGPR-direct wM ("a").
// Reconstruction (R15): sp=u1+2u2+2u3+u4, sq=u1+u2+u3; S1=sum sp_n,
// S23=sum (99-n)sp_n+sq_n; p_T=p0-dt6*W*S1, q_T=q0+dt*100*p0-dt*dt6*W*S23.
// FULL unroll on every reg-array access (R4: dynamic index => scratch).
// Numerics: f16 storage (W, M, u, S), fp32 MFMA accum + fp32 z1/P state.

typedef _Float16 v8h __attribute__((ext_vector_type(8)));
typedef float v4f __attribute__((ext_vector_type(4)));

#define NSTEPS 100
#define WS 264    // wldsT row stride (f16): row = one W-COLUMN, 16B-aligned
#define US 288    // ubuf row stride, f16 (576 B == 64 mod 128: bank-split)

// D(+=C) in VGPRs, A (packed-vector frag) in VGPRs, B (M-frag) from AGPRs.
#define MFMA_AV(C, A, B) \
    asm("v_mfma_f32_16x16x32_f16 %0, %1, %2, %0" : "+v"(C) : "v"(A), "a"(B))

__global__ __launch_bounds__(512, 2)
void ham_kernel(const float* __restrict__ x0, const float* __restrict__ W1,
                const float* __restrict__ b1, const float* __restrict__ W2,
                float* __restrict__ out)
{
    __shared__ __align__(16)  _Float16 wldsT[256 * WS];  // 135168 B: W^T (f16)
    __shared__ __align__(16)  float    mscr[8 * 640];    // 20480 B: M scratch
    __shared__ __align__(128) _Float16 ubuf[4 * US];     // 2304 B: 4 vec rows

    const int t = threadIdx.x;
    const int w = t >> 6;          // wave 0..7: owns tiles {2w, 2w+1}
    const int l = t & 63;
    const int quad = l >> 4;       // K-subgroup
    const int s = l & 15;          // owned column / A-row
    const int c0 = 32 * w + s;          // comp, tile 2w
    const int c1 = 32 * w + 16 + s;     // comp, tile 2w+1
    const int blk = blockIdx.x;
    const int sel = ((s & 3) == 1) ? US : 0;   // A-row m%4==1 -> 2nd vector

    // ---- stage W^T -> LDS f16: wldsT[c][r] = W[r][c] ----
    // thread t: column c = t&255, row half (t>>8)*128; coalesced global reads.
    {
        const int c = t & 255;
        const int rbase = (t >> 8) * 128;
        #pragma unroll 1
        for (int r0 = 0; r0 < 128; r0 += 8) {
            v8h h;
            #pragma unroll
            for (int j = 0; j < 8; ++j)
                h[j] = (_Float16)W1[(rbase + r0 + j) * 256 + c];
            *(v8h*)(wldsT + c * WS + rbase + r0) = h;   // b128, one-time
        }
    }
    __syncthreads();

    // ---- wF: own-column W^T frags (B-op), contiguous b128 from wldsT ----
    // wF{0,1}[kk][j] = W[32kk+8quad+j][c] = wldsT[c*WS + 32kk+8quad+j]
    v8h wF0[8], wF1[8];
    #pragma unroll
    for (int kk = 0; kk < 8; ++kk) {
        wF0[kk] = *(const v8h*)(wldsT + c0 * WS + 32 * kk + 8 * quad);
        wF1[kk] = *(const v8h*)(wldsT + c1 * WS + 32 * kk + 8 * quad);
    }

    // ---- build M = W^T W column-block frags wM0/wM1 (B-op: M[k][c]) ----
    v8h wM0[8], wM1[8];
    float* scr0 = mscr + w * 640;
    float* scr1 = scr0 + 320;
    #pragma unroll
    for (int kb = 0; kb < 16; ++kb) {
        v8h aM[8];   // A[m=s][k=8quad+j] = wldsT[(16kb+s)*WS + 32kk+8quad+j]
        #pragma unroll
        for (int kk = 0; kk < 8; ++kk)
            aM[kk] = *(const v8h*)(wldsT + (16 * kb + s) * WS
                                          + 32 * kk + 8 * quad);
        v4f D0 = {0.f,0.f,0.f,0.f}, D1 = {0.f,0.f,0.f,0.f};
        #pragma unroll
        for (int kk = 0; kk < 8; ++kk) {
            D0 = __builtin_amdgcn_mfma_f32_16x16x32_f16(aM[kk], wF0[kk], D0, 0, 0, 0);
            D1 = __builtin_amdgcn_mfma_f32_16x16x32_f16(aM[kk], wF1[kk], D1, 0, 0, 0);
        }
        *(v4f*)(scr0 + s * 20 + 4 * quad) = D0;
        *(v4f*)(scr1 + s * 20 + 4 * quad) = D1;
        asm volatile("s_waitcnt lgkmcnt(0)" ::: "memory");  // in-wave x-lane
        if ((quad >> 1) == (kb & 1)) {
            #pragma unroll
            for (int j = 0; j < 8; ++j) {
                wM0[kb >> 1][j] = (_Float16)scr0[s * 20 + 8 * (quad & 1) + j];
                wM1[kb >> 1][j] = (_Float16)scr1[s * 20 + 8 * (quad & 1) + j];
            }
        }
        asm volatile("s_waitcnt lgkmcnt(0)" ::: "memory");
    }

    const float b1r0 = b1[c0], b1r1 = b1[c1];
    const float w2r0 = W2[c0], w2r1 = W2[c1];
    float2 qp0 = ((const float2*)(x0 + (size_t)blk * 512))[c0];
    float2 qp1 = ((const float2*)(x0 + (size_t)blk * 512))[c1];
    const float q0o0 = qp0.x, p0o0 = qp0.y;
    const float q0o1 = qp1.x, p0o1 = qp1.y;

    // ---- prologue: rows {q0, p0} -> z1 = W^T q0 + b1 (Cs[0]), P (Cs[1]) ----
    if (quad == 0) {
        ubuf[c0] = (_Float16)q0o0;  ubuf[c1] = (_Float16)q0o1;
        ubuf[US + c0] = (_Float16)p0o0;  ubuf[US + c1] = (_Float16)p0o1;
    }
    __syncthreads();
    float z10, P0, z11, P1;
    {
        const _Float16* ab = ubuf + sel + 8 * quad;
        v4f C0a = {0.f,0.f,0.f,0.f}, C0b = {0.f,0.f,0.f,0.f};
        v4f C1a = {0.f,0.f,0.f,0.f}, C1b = {0.f,0.f,0.f,0.f};
        #pragma unroll
        for (int kk = 0; kk < 8; kk += 2) {
            v8h a0 = *(const v8h*)(ab + 32 * kk);
            v8h a1 = *(const v8h*)(ab + 32 * (kk + 1));
            C0a = __builtin_amdgcn_mfma_f32_16x16x32_f16(a0, wF0[kk], C0a, 0, 0, 0);
            C1a = __builtin_amdgcn_mfma_f32_16x16x32_f16(a0, wF1[kk], C1a, 0, 0, 0);
            C0b = __builtin_amdgcn_mfma_f32_16x16x32_f16(a1, wF0[kk + 1], C0b, 0, 0, 0);
            C1b = __builtin_amdgcn_mfma_f32_16x16x32_f16(a1, wF1[kk + 1], C1b, 0, 0, 0);
        }
        v4f C0s = C0a + C0b, C1s = C1a + C1b;
        z10 = C0s[0] + b1r0;  P0 = C0s[1];
        z11 = C1s[0] + b1r1;  P1 = C1s[1];
    }
    __syncthreads();   // protect ubuf before loop overwrites

    const float dt = 0.01f, hdt = 0.005f, dt6 = 0.01f / 6.f;
    const float dtdt6 = dt * dt6, hdt2 = hdt * hdt, dthdt = dt * hdt;

    float S10 = 0.f, S230 = 0.f, S11 = 0.f, S231 = 0.f, cn = 99.f;

    #pragma unroll 1
    for (int n = 0; n < NSTEPS; ++n) {
        // ======== phase A: u1, u2 (both comps) -> packed MFMA -> Y1, Y2 ====
        float z20 = z10 + hdt * P0, z21 = z11 + hdt * P1;
        float e10 = __expf(2.f * z10), e20 = __expf(2.f * z20);
        float e11 = __expf(2.f * z11), e21 = __expf(2.f * z21);
        float h10 = 1.f - 2.f / (e10 + 1.f), h20 = 1.f - 2.f / (e20 + 1.f);
        float h11 = 1.f - 2.f / (e11 + 1.f), h21 = 1.f - 2.f / (e21 + 1.f);
        float u10 = (1.f - h10 * h10) * w2r0, u20 = (1.f - h20 * h20) * w2r0;
        float u11 = (1.f - h11 * h11) * w2r1, u21 = (1.f - h21 * h21) * w2r1;
        if (quad == 0) {
            ubuf[c0] = (_Float16)u10;       ubuf[c1] = (_Float16)u11;
            ubuf[US + c0] = (_Float16)u20;  ubuf[US + c1] = (_Float16)u21;
        }
        __syncthreads();

        float Y10, Y20, Y11, Y21;
        {
            const _Float16* ab = ubuf + sel + 8 * quad;
            v4f C0a = {0.f,0.f,0.f,0.f}, C0b = {0.f,0.f,0.f,0.f};
            v4f C1a = {0.f,0.f,0.f,0.f}, C1b = {0.f,0.f,0.f,0.f};
            #pragma unroll
            for (int kk = 0; kk < 8; kk += 2) {
                v8h a0 = *(const v8h*)(ab + 32 * kk);
                v8h a1 = *(const v8h*)(ab + 32 * (kk + 1));
                MFMA_AV(C0a, a0, wM0[kk]);
                MFMA_AV(C1a, a0, wM1[kk]);
                MFMA_AV(C0b, a1, wM0[kk + 1]);
                MFMA_AV(C1b, a1, wM1[kk + 1]);
            }
            v4f C0s = C0a + C0b, C1s = C1a + C1b;
            Y10 = C0s[0];  Y20 = C0s[1];
            Y11 = C1s[0];  Y21 = C1s[1];
        }

        // ======== phase B: u3, u4 -> packed MFMA -> Y3, Y4 ========
        float z30 = z10 + hdt * P0 - hdt2 * Y10;
        float z40 = z10 + dt * P0 - dthdt * Y20;
        float z31 = z11 + hdt * P1 - hdt2 * Y11;
        float z41 = z11 + dt * P1 - dthdt * Y21;
        float e30 = __expf(2.f * z30), e40 = __expf(2.f * z40);
        float e31 = __expf(2.f * z31), e41 = __expf(2.f * z41);
        float h30 = 1.f - 2.f / (e30 + 1.f), h40 = 1.f - 2.f / (e40 + 1.f);
        float h31 = 1.f - 2.f / (e31 + 1.f), h41 = 1.f - 2.f / (e41 + 1.f);
        float u30 = (1.f - h30 * h30) * w2r0, u40 = (1.f - h40 * h40) * w2r0;
        float u31 = (1.f - h31 * h31) * w2r1, u41 = (1.f - h41 * h41) * w2r1;
        if (quad == 0) {
            ubuf[2 * US + c0] = (_Float16)u30;  ubuf[2 * US + c1] = (_Float16)u31;
            ubuf[3 * US + c0] = (_Float16)u40;  ubuf[3 * US + c1] = (_Float16)u41;
        }
        __syncthreads();

        float Y30, Y40, Y31, Y41;
        {
            const _Float16* ab = ubuf + 2 * US + sel + 8 * quad;
            v4f C0a = {0.f,0.f,0.f,0.f}, C0b = {0.f,0.f,0.f,0.f};
            v4f C1a = {0.f,0.f,0.f,0.f}, C1b = {0.f,0.f,0.f,0.f};
            #pragma unroll
            for (int kk = 0; kk < 8; kk += 2) {
                v8h a0 = *(const v8h*)(ab + 32 * kk);
                v8h a1 = *(const v8h*)(ab + 32 * (kk + 1));
                MFMA_AV(C0a, a0, wM0[kk]);
                MFMA_AV(C1a, a0, wM1[kk]);
                MFMA_AV(C0b, a1, wM0[kk + 1]);
                MFMA_AV(C1b, a1, wM1[kk + 1]);
            }
            v4f C0s = C0a + C0b, C1s = C1a + C1b;
            Y30 = C0s[0];  Y40 = C0s[1];
            Y31 = C1s[0];  Y41 = C1s[1];
        }

        // ======== step update (z1 uses OLD P), both comps ========
        z10 = z10 + dt * P0 - dtdt6 * (Y10 + Y20 + Y30);
        P0  = P0 - dt6 * (Y10 + 2.f * Y20 + 2.f * Y30 + Y40);
        z11 = z11 + dt * P1 - dtdt6 * (Y11 + Y21 + Y31);
        P1  = P1 - dt6 * (Y11 + 2.f * Y21 + 2.f * Y31 + Y41);
        float sp0 = u10 + 2.f * u20 + 2.f * u30 + u40;
        float sq0 = u10 + u20 + u30;
        float sp1 = u11 + 2.f * u21 + 2.f * u31 + u41;
        float sq1 = u11 + u21 + u31;
        S10 += sp0; S230 += cn * sp0 + sq0;
        S11 += sp1; S231 += cn * sp1 + sq1;
        cn -= 1.f;
    }

    // ---- epilogue: rows {S1, S23}: p_T = p0 - dt6*W*S1;
    //      q_T = q0 + dt*100*p0 - dt*dt6*W*S23 ----
    __syncthreads();   // all waves done reading ubuf before rewrite
    if (quad == 0) {
        ubuf[c0] = (_Float16)S10;       ubuf[c1] = (_Float16)S11;
        ubuf[US + c0] = (_Float16)S230; ubuf[US + c1] = (_Float16)S231;
    }
    __syncthreads();
    // wBt[i][kk][j] = W[c][32kk+8quad+j] = wldsT[(32kk+8quad+j)*WS + c]
    v8h wBt0[8], wBt1[8];
    #pragma unroll
    for (int kk = 0; kk < 8; ++kk)
        #pragma unroll
        for (int j = 0; j < 8; ++j) {
            wBt0[kk][j] = wldsT[(32 * kk + 8 * quad + j) * WS + c0];
            wBt1[kk][j] = wldsT[(32 * kk + 8 * quad + j) * WS + c1];
        }
    float D10, D20, D11, D21;
    {
        const _Float16* ab = ubuf + sel + 8 * quad;
        v4f C0a = {0.f,0.f,0.f,0.f}, C0b = {0.f,0.f,0.f,0.f};
        v4f C1a = {0.f,0.f,0.f,0.f}, C1b = {0.f,0.f,0.f,0.f};
        #pragma unroll
        for (int kk = 0; kk < 8; kk += 2) {
            v8h a0 = *(const v8h*)(ab + 32 * kk);
            v8h a1 = *(const v8h*)(ab + 32 * (kk + 1));
            C0a = __builtin_amdgcn_mfma_f32_16x16x32_f16(a0, wBt0[kk], C0a, 0, 0, 0);
            C1a = __builtin_amdgcn_mfma_f32_16x16x32_f16(a0, wBt1[kk], C1a, 0, 0, 0);
            C0b = __builtin_amdgcn_mfma_f32_16x16x32_f16(a1, wBt0[kk + 1], C0b, 0, 0, 0);
            C1b = __builtin_amdgcn_mfma_f32_16x16x32_f16(a1, wBt1[kk + 1], C1b, 0, 0, 0);
        }
        v4f C0s = C0a + C0b, C1s = C1a + C1b;
        D10 = C0s[0];  D20 = C0s[1];
        D11 = C1s[0];  D21 = C1s[1];
    }
    float pT0 = p0o0 - dt6 * D10;
    float qT0 = q0o0 + dt * (float)NSTEPS * p0o0 - dtdt6 * D20;
    float pT1 = p0o1 - dt6 * D11;
    float qT1 = q0o1 + dt * (float)NSTEPS * p0o1 - dtdt6 * D21;

    if (quad == 0) {
        ((float2*)(out + (size_t)blk * 512))[c0] = make_float2(qT0, pT0);
        ((float2*)(out + (size_t)blk * 512))[c1] = make_float2(qT1, pT1);
    }
}

extern "C" void kernel_launch(void* const* d_in, const int* in_sizes, int n_in,
                              void* d_out, int out_size, void* d_ws, size_t ws_size,
                              hipStream_t stream) {
    const float* x0 = (const float*)d_in[0];
    const float* W1 = (const float*)d_in[1];
    const float* b1 = (const float*)d_in[2];
    const float* W2 = (const float*)d_in[3];
    // d_in[4] = b2: constant offset, no effect on the gradient/dynamics.
    float* out = (float*)d_out;
    hipLaunchKernelGGL(ham_kernel, dim3(256), dim3(512), 0, stream,
                       x0, W1, b1, W2, out);
}

// Round 22
// 167.679 us; speedup vs baseline: 1.4190x; 1.2736x over previous
//
#include <hip/hip_runtime.h>
#include <stdint.h>

// HamiltonianFlow: x [256, 8, 32, 2] (q,p); H = 0.5*sum(p^2) + MLP(q).
// dq/dt = p, dp/dt = -W u(z), z = W^T q + b1, u = (1-tanh^2(z)).*W2.
// 100 RK4 steps, z-space iteration with M = W^T W (R15-R21 verified):
//   z2 = z1+hdt*P; z3 = z1+hdt*P-hdt^2*Y1; z4 = z1+dt*P-dt*hdt*Y2; Y_i = M u_i
//   z1' = z1+dt*P-dt*dt6*(Y1+Y2+Y3);  P' = P-dt6*(Y1+2Y2+2Y3+Y4)
// Phase A: u1,u2 -> {Y1,Y2}; phase B: u3,u4 -> {Y3,Y4}. 1 barrier/phase,
// 200 phases (RK4 dependency minimum; grid pinned 256 blocks = 1/CU).
//
// R22 = R21 + QUAD-SPLIT NONLINEARITY. R21: VALUBusy 52% of which ~500cyc/
// phase was scalar VALU -- each lane redundantly ran 4 tanh chains (2 comps
// x 2 stages, duplicated across quads). Now quad q owns one (comp,stage):
//   quad0->(c0,s1) quad1->(c0,s2) quad2->(c1,s1) quad3->(c1,s2)
// (phase B: s3/s4 same pattern). 1 exp+rcp per lane per phase (was 4);
// ds_write with FULL exec (64 lanes write 64 distinct comps, covering both
// vector rows exactly). S1/S23 kept as per-lane partials with quad weights
// (quad&1: sp 2,1 / sq 1,0; else sp 1,2 / sq 1,1); one __shfl_xor(16) pair
// in the epilogue reduces quad0+1 (c0) and quad2+3 (c1). u values are
// bit-identical to R21 -> absmax must not move.
// Everything else R21-verified: 8 waves x 2 tiles (2/SIMD overlap),
// transposed W^T staging (contiguous b128 wF/aM), packed-pair A rows
// (m%4==0 vec1 / m%4==1 vec2, US=288 bank-split), AGPR-direct wM ("a"),
// in-lane Y extraction (Y_vec1=Cs[0], Y_vec2=Cs[1]).
// FULL unroll on every reg-array access (R4: dynamic index => scratch).
// Numerics: f16 storage (W, M, u, S), fp32 MFMA accum + fp32 z1/P state.

typedef _Float16 v8h __attribute__((ext_vector_type(8)));
typedef float v4f __attribute__((ext_vector_type(4)));

#define NSTEPS 100
#define WS 264    // wldsT row stride (f16): row = one W-COLUMN, 16B-aligned
#define US 288    // ubuf row stride, f16 (576 B == 64 mod 128: bank-split)

// D(+=C) in VGPRs, A (packed-vector frag) in VGPRs, B (M-frag) from AGPRs.
#define MFMA_AV(C, A, B) \
    asm("v_mfma_f32_16x16x32_f16 %0, %1, %2, %0" : "+v"(C) : "v"(A), "a"(B))

__global__ __launch_bounds__(512, 2)
void ham_kernel(const float* __restrict__ x0, const float* __restrict__ W1,
                const float* __restrict__ b1, const float* __restrict__ W2,
                float* __restrict__ out)
{
    __shared__ __align__(16)  _Float16 wldsT[256 * WS];  // 135168 B: W^T (f16)
    __shared__ __align__(16)  float    mscr[8 * 640];    // 20480 B: M scratch
    __shared__ __align__(128) _Float16 ubuf[4 * US];     // 2304 B: 4 vec rows

    const int t = threadIdx.x;
    const int w = t >> 6;          // wave 0..7: owns tiles {2w, 2w+1}
    const int l = t & 63;
    const int quad = l >> 4;       // K-subgroup / nonlinearity slot
    const int s = l & 15;          // owned column / A-row
    const int c0 = 32 * w + s;          // comp, tile 2w
    const int c1 = 32 * w + 16 + s;     // comp, tile 2w+1
    const int blk = blockIdx.x;
    const int sel = ((s & 3) == 1) ? US : 0;   // A-row m%4==1 -> 2nd vector
    const int cq   = (quad & 2) ? c1 : c0;     // quad's assigned comp
    const int wrA  = ((quad & 1) ? US : 0) + cq;        // phase-A write slot
    const int wrB  = wrA + 2 * US;                      // phase-B write slot

    // ---- stage W^T -> LDS f16: wldsT[c][r] = W[r][c] ----
    {
        const int c = t & 255;
        const int rbase = (t >> 8) * 128;
        #pragma unroll 1
        for (int r0 = 0; r0 < 128; r0 += 8) {
            v8h h;
            #pragma unroll
            for (int j = 0; j < 8; ++j)
                h[j] = (_Float16)W1[(rbase + r0 + j) * 256 + c];
            *(v8h*)(wldsT + c * WS + rbase + r0) = h;   // b128, one-time
        }
    }
    __syncthreads();

    // ---- wF: own-column W^T frags (B-op), contiguous b128 from wldsT ----
    v8h wF0[8], wF1[8];
    #pragma unroll
    for (int kk = 0; kk < 8; ++kk) {
        wF0[kk] = *(const v8h*)(wldsT + c0 * WS + 32 * kk + 8 * quad);
        wF1[kk] = *(const v8h*)(wldsT + c1 * WS + 32 * kk + 8 * quad);
    }

    // ---- build M = W^T W column-block frags wM0/wM1 (B-op: M[k][c]) ----
    v8h wM0[8], wM1[8];
    float* scr0 = mscr + w * 640;
    float* scr1 = scr0 + 320;
    #pragma unroll
    for (int kb = 0; kb < 16; ++kb) {
        v8h aM[8];   // A[m=s][k=8quad+j] = wldsT[(16kb+s)*WS + 32kk+8quad+j]
        #pragma unroll
        for (int kk = 0; kk < 8; ++kk)
            aM[kk] = *(const v8h*)(wldsT + (16 * kb + s) * WS
                                          + 32 * kk + 8 * quad);
        v4f D0 = {0.f,0.f,0.f,0.f}, D1 = {0.f,0.f,0.f,0.f};
        #pragma unroll
        for (int kk = 0; kk < 8; ++kk) {
            D0 = __builtin_amdgcn_mfma_f32_16x16x32_f16(aM[kk], wF0[kk], D0, 0, 0, 0);
            D1 = __builtin_amdgcn_mfma_f32_16x16x32_f16(aM[kk], wF1[kk], D1, 0, 0, 0);
        }
        *(v4f*)(scr0 + s * 20 + 4 * quad) = D0;
        *(v4f*)(scr1 + s * 20 + 4 * quad) = D1;
        asm volatile("s_waitcnt lgkmcnt(0)" ::: "memory");  // in-wave x-lane
        if ((quad >> 1) == (kb & 1)) {
            #pragma unroll
            for (int j = 0; j < 8; ++j) {
                wM0[kb >> 1][j] = (_Float16)scr0[s * 20 + 8 * (quad & 1) + j];
                wM1[kb >> 1][j] = (_Float16)scr1[s * 20 + 8 * (quad & 1) + j];
            }
        }
        asm volatile("s_waitcnt lgkmcnt(0)" ::: "memory");
    }

    const float b1r0 = b1[c0], b1r1 = b1[c1];
    const float w2r0 = W2[c0], w2r1 = W2[c1];
    const float w2q  = (quad & 2) ? w2r1 : w2r0;   // quad's assigned W2
    float2 qp0 = ((const float2*)(x0 + (size_t)blk * 512))[c0];
    float2 qp1 = ((const float2*)(x0 + (size_t)blk * 512))[c1];
    const float q0o0 = qp0.x, p0o0 = qp0.y;
    const float q0o1 = qp1.x, p0o1 = qp1.y;

    // ---- prologue: rows {q0, p0} -> z1 = W^T q0 + b1 (Cs[0]), P (Cs[1]) ----
    if (quad == 0) {
        ubuf[c0] = (_Float16)q0o0;  ubuf[c1] = (_Float16)q0o1;
        ubuf[US + c0] = (_Float16)p0o0;  ubuf[US + c1] = (_Float16)p0o1;
    }
    __syncthreads();
    float z10, P0, z11, P1;
    {
        const _Float16* ab = ubuf + sel + 8 * quad;
        v4f C0a = {0.f,0.f,0.f,0.f}, C0b = {0.f,0.f,0.f,0.f};
        v4f C1a = {0.f,0.f,0.f,0.f}, C1b = {0.f,0.f,0.f,0.f};
        #pragma unroll
        for (int kk = 0; kk < 8; kk += 2) {
            v8h a0 = *(const v8h*)(ab + 32 * kk);
            v8h a1 = *(const v8h*)(ab + 32 * (kk + 1));
            C0a = __builtin_amdgcn_mfma_f32_16x16x32_f16(a0, wF0[kk], C0a, 0, 0, 0);
            C1a = __builtin_amdgcn_mfma_f32_16x16x32_f16(a0, wF1[kk], C1a, 0, 0, 0);
            C0b = __builtin_amdgcn_mfma_f32_16x16x32_f16(a1, wF0[kk + 1], C0b, 0, 0, 0);
            C1b = __builtin_amdgcn_mfma_f32_16x16x32_f16(a1, wF1[kk + 1], C1b, 0, 0, 0);
        }
        v4f C0s = C0a + C0b, C1s = C1a + C1b;
        z10 = C0s[0] + b1r0;  P0 = C0s[1];
        z11 = C1s[0] + b1r1;  P1 = C1s[1];
    }
    __syncthreads();   // protect ubuf before loop overwrites

    const float dt = 0.01f, hdt = 0.005f, dt6 = 0.01f / 6.f;
    const float dtdt6 = dt * dt6, hdt2 = hdt * hdt, dthdt = dt * hdt;
    const float wspA = (quad & 1) ? 2.f : 1.f;   // sp weight, phase-A u
    const float wspB = (quad & 1) ? 1.f : 2.f;   // sp weight, phase-B u
    const float wsqB = (quad & 1) ? 0.f : 1.f;   // sq weight, phase-B u

    float S1p = 0.f, S23p = 0.f, cn = 99.f;

    #pragma unroll 1
    for (int n = 0; n < NSTEPS; ++n) {
        // ======== phase A: quad-assigned u (stage 1 or 2) ========
        float z20 = z10 + hdt * P0, z21 = z11 + hdt * P1;
        float zA1 = (quad & 2) ? z11 : z10;
        float zA2 = (quad & 2) ? z21 : z20;
        float zA  = (quad & 1) ? zA2 : zA1;
        float eA = __expf(2.f * zA);
        float hA = 1.f - 2.f / (eA + 1.f);
        float uA = (1.f - hA * hA) * w2q;
        ubuf[wrA] = (_Float16)uA;              // full-exec: 64 distinct slots
        __syncthreads();

        float Y10, Y20, Y11, Y21;
        {
            const _Float16* ab = ubuf + sel + 8 * quad;
            v4f C0a = {0.f,0.f,0.f,0.f}, C0b = {0.f,0.f,0.f,0.f};
            v4f C1a = {0.f,0.f,0.f,0.f}, C1b = {0.f,0.f,0.f,0.f};
            #pragma unroll
            for (int kk = 0; kk < 8; kk += 2) {
                v8h a0 = *(const v8h*)(ab + 32 * kk);
                v8h a1 = *(const v8h*)(ab + 32 * (kk + 1));
                MFMA_AV(C0a, a0, wM0[kk]);
                MFMA_AV(C1a, a0, wM1[kk]);
                MFMA_AV(C0b, a1, wM0[kk + 1]);
                MFMA_AV(C1b, a1, wM1[kk + 1]);
            }
            v4f C0s = C0a + C0b, C1s = C1a + C1b;
            Y10 = C0s[0];  Y20 = C0s[1];
            Y11 = C1s[0];  Y21 = C1s[1];
        }

        // ======== phase B: quad-assigned u (stage 3 or 4) ========
        float z30 = z10 + hdt * P0 - hdt2 * Y10;
        float z40 = z10 + dt * P0 - dthdt * Y20;
        float z31 = z11 + hdt * P1 - hdt2 * Y11;
        float z41 = z11 + dt * P1 - dthdt * Y21;
        float zB3 = (quad & 2) ? z31 : z30;
        float zB4 = (quad & 2) ? z41 : z40;
        float zB  = (quad & 1) ? zB4 : zB3;
        float eB = __expf(2.f * zB);
        float hB = 1.f - 2.f / (eB + 1.f);
        float uB = (1.f - hB * hB) * w2q;
        ubuf[wrB] = (_Float16)uB;              // full-exec: 64 distinct slots
        __syncthreads();

        float Y30, Y40, Y31, Y41;
        {
            const _Float16* ab = ubuf + 2 * US + sel + 8 * quad;
            v4f C0a = {0.f,0.f,0.f,0.f}, C0b = {0.f,0.f,0.f,0.f};
            v4f C1a = {0.f,0.f,0.f,0.f}, C1b = {0.f,0.f,0.f,0.f};
            #pragma unroll
            for (int kk = 0; kk < 8; kk += 2) {
                v8h a0 = *(const v8h*)(ab + 32 * kk);
                v8h a1 = *(const v8h*)(ab + 32 * (kk + 1));
                MFMA_AV(C0a, a0, wM0[kk]);
                MFMA_AV(C1a, a0, wM1[kk]);
                MFMA_AV(C0b, a1, wM0[kk + 1]);
                MFMA_AV(C1b, a1, wM1[kk + 1]);
            }
            v4f C0s = C0a + C0b, C1s = C1a + C1b;
            Y30 = C0s[0];  Y40 = C0s[1];
            Y31 = C1s[0];  Y41 = C1s[1];
        }

        // ======== step update (z1 uses OLD P); per-lane S partials ========
        z10 = z10 + dt * P0 - dtdt6 * (Y10 + Y20 + Y30);
        P0  = P0 - dt6 * (Y10 + 2.f * Y20 + 2.f * Y30 + Y40);
        z11 = z11 + dt * P1 - dtdt6 * (Y11 + Y21 + Y31);
        P1  = P1 - dt6 * (Y11 + 2.f * Y21 + 2.f * Y31 + Y41);
        float sp = wspA * uA + wspB * uB;
        float sq = uA + wsqB * uB;
        S1p += sp; S23p += cn * sp + sq;
        cn -= 1.f;
    }

    // ---- epilogue: reduce S partials (quad0+1 -> c0, quad2+3 -> c1) ----
    S1p  += __shfl_xor(S1p, 16, 64);
    S23p += __shfl_xor(S23p, 16, 64);
    __syncthreads();   // all waves done reading ubuf before rewrite
    if ((quad & 1) == 0) {
        ubuf[cq] = (_Float16)S1p;
        ubuf[US + cq] = (_Float16)S23p;
    }
    __syncthreads();
    // wBt[kk][j] = W[c][32kk+8quad+j] = wldsT[(32kk+8quad+j)*WS + c]
    v8h wBt0[8], wBt1[8];
    #pragma unroll
    for (int kk = 0; kk < 8; ++kk)
        #pragma unroll
        for (int j = 0; j < 8; ++j) {
            wBt0[kk][j] = wldsT[(32 * kk + 8 * quad + j) * WS + c0];
            wBt1[kk][j] = wldsT[(32 * kk + 8 * quad + j) * WS + c1];
        }
    float D10, D20, D11, D21;
    {
        const _Float16* ab = ubuf + sel + 8 * quad;
        v4f C0a = {0.f,0.f,0.f,0.f}, C0b = {0.f,0.f,0.f,0.f};
        v4f C1a = {0.f,0.f,0.f,0.f}, C1b = {0.f,0.f,0.f,0.f};
        #pragma unroll
        for (int kk = 0; kk < 8; kk += 2) {
            v8h a0 = *(const v8h*)(ab + 32 * kk);
            v8h a1 = *(const v8h*)(ab + 32 * (kk + 1));
            C0a = __builtin_amdgcn_mfma_f32_16x16x32_f16(a0, wBt0[kk], C0a, 0, 0, 0);
            C1a = __builtin_amdgcn_mfma_f32_16x16x32_f16(a0, wBt1[kk], C1a, 0, 0, 0);
            C0b = __builtin_amdgcn_mfma_f32_16x16x32_f16(a1, wBt0[kk + 1], C0b, 0, 0, 0);
            C1b = __builtin_amdgcn_mfma_f32_16x16x32_f16(a1, wBt1[kk + 1], C1b, 0, 0, 0);
        }
        v4f C0s = C0a + C0b, C1s = C1a + C1b;
        D10 = C0s[0];  D20 = C0s[1];
        D11 = C1s[0];  D21 = C1s[1];
    }
    const float dt6e = 0.01f / 6.f, dtdt6e = 0.01f * dt6e;
    float pT0 = p0o0 - dt6e * D10;
    float qT0 = q0o0 + 0.01f * (float)NSTEPS * p0o0 - dtdt6e * D20;
    float pT1 = p0o1 - dt6e * D11;
    float qT1 = q0o1 + 0.01f * (float)NSTEPS * p0o1 - dtdt6e * D21;

    if (quad == 0) {
        ((float2*)(out + (size_t)blk * 512))[c0] = make_float2(qT0, pT0);
        ((float2*)(out + (size_t)blk * 512))[c1] = make_float2(qT1, pT1);
    }
}

extern "C" void kernel_launch(void* const* d_in, const int* in_sizes, int n_in,
                              void* d_out, int out_size, void* d_ws, size_t ws_size,
                              hipStream_t stream) {
    const float* x0 = (const float*)d_in[0];
    const float* W1 = (const float*)d_in[1];
    const float* b1 = (const float*)d_in[2];
    const float* W2 = (const float*)d_in[3];
    // d_in[4] = b2: constant offset, no effect on the gradient/dynamics.
    float* out = (float*)d_out;
    hipLaunchKernelGGL(ham_kernel, dim3(256), dim3(512), 0, stream,
                       x0, W1, b1, W2, out);
}

// Round 23
// 140.551 us; speedup vs baseline: 1.6929x; 1.1930x over previous
//
#include <hip/hip_runtime.h>
#include <stdint.h>

// HamiltonianFlow: x [256, 8, 32, 2] (q,p); H = 0.5*sum(p^2) + MLP(q).
// dq/dt = p, dp/dt = -W u(z), z = W^T q + b1, u = (1-tanh^2(z)).*W2.
// 100 RK4 steps, z-space iteration with M = W^T W (R15-R22 verified):
//   z2 = z1+hdt*P; z3 = z1+hdt*P-hdt^2*Y1; z4 = z1+dt*P-dt*hdt*Y2; Y_i = M u_i
//   z1' = z1+dt*P-dt*dt6*(Y1+Y2+Y3);  P' = P-dt6*(Y1+2Y2+2Y3+Y4)
//
// R23: ONE PHASE PER STEP via LAGGED Y. Y enters z3/z4 with coefficients
// hdt^2=2.5e-5 and dt*hdt=5e-5; using the PREVIOUS step's Y1,Y2 there gives
// dz ~ 2.5e-5*|dY/step| ~ 2.5e-7 -- 100x below the f16 u-rounding (3e-5)
// that already dominates absmax. (z1'/P' still use exact current Ys.)
// So u1..u4 are all computable at the step top -> pack FOUR vectors into
// A rows m%4 = {0,1,2,3} (vector = s&3); D row = 4*quad+reg => reg r holds
// Y_{r+1}: ALL FOUR Ys in-lane, both tiles. Per wave per STEP: 8 A-reads,
// 16 MFMAs, 1 barrier (R22: 16 reads, 32 MFMAs, 2 barriers).
// ubuf row stride US=272 f16 (544 B == 32 mod 128): the 4 vector rows land
// on 4 distinct bank quarters; residual aliasing 2-way = free (m136).
// Quad-split nonlinearity (R22): quad q computes stage q+1 for BOTH comps
// (2 exp/lane/step); stage weights wsp={1,2,2,1}, wsq={1,1,1,0}; S partials
// reduced by shfl_xor(16)+shfl_xor(32) in the epilogue.
// Everything else R21/R22-verified: 8 waves x 2 tiles (2/SIMD), transposed
// W^T staging (contiguous b128 wF/aM), AGPR-direct wM ("a" constraint),
// M-build scr stride 20. Reconstruction (R15): sp=u1+2u2+2u3+u4,
// sq=u1+u2+u3; S1=sum sp_n, S23=sum (99-n)sp_n+sq_n;
// p_T = p0-dt6*W*S1, q_T = q0+dt*100*p0-dt*dt6*W*S23.
// FULL unroll on every reg-array access (R4: dynamic index => scratch).
// Numerics: f16 storage (W, M, u, S), fp32 MFMA accum + fp32 z1/P state.

typedef _Float16 v8h __attribute__((ext_vector_type(8)));
typedef float v4f __attribute__((ext_vector_type(4)));

#define NSTEPS 100
#define WS 264    // wldsT row stride (f16): row = one W-COLUMN, 16B-aligned
#define US 272    // ubuf row stride, f16 (544 B == 32 mod 128: 4-way split)

// D(+=C) in VGPRs, A (packed-vector frag) in VGPRs, B (M-frag) from AGPRs.
#define MFMA_AV(C, A, B) \
    asm("v_mfma_f32_16x16x32_f16 %0, %1, %2, %0" : "+v"(C) : "v"(A), "a"(B))

__global__ __launch_bounds__(512, 2)
void ham_kernel(const float* __restrict__ x0, const float* __restrict__ W1,
                const float* __restrict__ b1, const float* __restrict__ W2,
                float* __restrict__ out)
{
    __shared__ __align__(16)  _Float16 wldsT[256 * WS];  // 135168 B: W^T (f16)
    __shared__ __align__(16)  float    mscr[8 * 640];    // 20480 B: M scratch
    __shared__ __align__(128) _Float16 ubuf[4 * US];     // 2176 B: 4 vec rows

    const int t = threadIdx.x;
    const int w = t >> 6;          // wave 0..7: owns tiles {2w, 2w+1}
    const int l = t & 63;
    const int quad = l >> 4;       // K-subgroup / stage slot (stage quad+1)
    const int s = l & 15;          // owned column / A-row
    const int c0 = 32 * w + s;          // comp, tile 2w
    const int c1 = 32 * w + 16 + s;     // comp, tile 2w+1
    const int blk = blockIdx.x;
    const int sel = (s & 3) * US;  // A-row m%4 = r -> vector r

    // ---- stage W^T -> LDS f16: wldsT[c][r] = W[r][c] ----
    {
        const int c = t & 255;
        const int rbase = (t >> 8) * 128;
        #pragma unroll 1
        for (int r0 = 0; r0 < 128; r0 += 8) {
            v8h h;
            #pragma unroll
            for (int j = 0; j < 8; ++j)
                h[j] = (_Float16)W1[(rbase + r0 + j) * 256 + c];
            *(v8h*)(wldsT + c * WS + rbase + r0) = h;   // b128, one-time
        }
    }
    __syncthreads();

    // ---- wF: own-column W^T frags (B-op), contiguous b128 from wldsT ----
    v8h wF0[8], wF1[8];
    #pragma unroll
    for (int kk = 0; kk < 8; ++kk) {
        wF0[kk] = *(const v8h*)(wldsT + c0 * WS + 32 * kk + 8 * quad);
        wF1[kk] = *(const v8h*)(wldsT + c1 * WS + 32 * kk + 8 * quad);
    }

    // ---- build M = W^T W column-block frags wM0/wM1 (B-op: M[k][c]) ----
    v8h wM0[8], wM1[8];
    float* scr0 = mscr + w * 640;
    float* scr1 = scr0 + 320;
    #pragma unroll
    for (int kb = 0; kb < 16; ++kb) {
        v8h aM[8];   // A[m=s][k=8quad+j] = wldsT[(16kb+s)*WS + 32kk+8quad+j]
        #pragma unroll
        for (int kk = 0; kk < 8; ++kk)
            aM[kk] = *(const v8h*)(wldsT + (16 * kb + s) * WS
                                          + 32 * kk + 8 * quad);
        v4f D0 = {0.f,0.f,0.f,0.f}, D1 = {0.f,0.f,0.f,0.f};
        #pragma unroll
        for (int kk = 0; kk < 8; ++kk) {
            D0 = __builtin_amdgcn_mfma_f32_16x16x32_f16(aM[kk], wF0[kk], D0, 0, 0, 0);
            D1 = __builtin_amdgcn_mfma_f32_16x16x32_f16(aM[kk], wF1[kk], D1, 0, 0, 0);
        }
        *(v4f*)(scr0 + s * 20 + 4 * quad) = D0;
        *(v4f*)(scr1 + s * 20 + 4 * quad) = D1;
        asm volatile("s_waitcnt lgkmcnt(0)" ::: "memory");  // in-wave x-lane
        if ((quad >> 1) == (kb & 1)) {
            #pragma unroll
            for (int j = 0; j < 8; ++j) {
                wM0[kb >> 1][j] = (_Float16)scr0[s * 20 + 8 * (quad & 1) + j];
                wM1[kb >> 1][j] = (_Float16)scr1[s * 20 + 8 * (quad & 1) + j];
            }
        }
        asm volatile("s_waitcnt lgkmcnt(0)" ::: "memory");
    }

    const float b1r0 = b1[c0], b1r1 = b1[c1];
    const float w2r0 = W2[c0], w2r1 = W2[c1];
    float2 qp0 = ((const float2*)(x0 + (size_t)blk * 512))[c0];
    float2 qp1 = ((const float2*)(x0 + (size_t)blk * 512))[c1];
    const float q0o0 = qp0.x, p0o0 = qp0.y;
    const float q0o1 = qp1.x, p0o1 = qp1.y;

    // ---- prologue: rows {q0, p0} -> z1 = W^T q0 + b1 (C[0]), P (C[1]) ----
    if (quad == 0) {
        ubuf[c0] = (_Float16)q0o0;  ubuf[c1] = (_Float16)q0o1;
        ubuf[US + c0] = (_Float16)p0o0;  ubuf[US + c1] = (_Float16)p0o1;
        // zero rows 2,3 so prologue A-frags are garbage-free
        ubuf[2 * US + c0] = (_Float16)0.f;  ubuf[2 * US + c1] = (_Float16)0.f;
        ubuf[3 * US + c0] = (_Float16)0.f;  ubuf[3 * US + c1] = (_Float16)0.f;
    }
    __syncthreads();
    float z10, P0, z11, P1;
    {
        const _Float16* ab = ubuf + sel + 8 * quad;
        v4f C0a = {0.f,0.f,0.f,0.f}, C0b = {0.f,0.f,0.f,0.f};
        v4f C1a = {0.f,0.f,0.f,0.f}, C1b = {0.f,0.f,0.f,0.f};
        #pragma unroll
        for (int kk = 0; kk < 8; kk += 2) {
            v8h a0 = *(const v8h*)(ab + 32 * kk);
            v8h a1 = *(const v8h*)(ab + 32 * (kk + 1));
            C0a = __builtin_amdgcn_mfma_f32_16x16x32_f16(a0, wF0[kk], C0a, 0, 0, 0);
            C1a = __builtin_amdgcn_mfma_f32_16x16x32_f16(a0, wF1[kk], C1a, 0, 0, 0);
            C0b = __builtin_amdgcn_mfma_f32_16x16x32_f16(a1, wF0[kk + 1], C0b, 0, 0, 0);
            C1b = __builtin_amdgcn_mfma_f32_16x16x32_f16(a1, wF1[kk + 1], C1b, 0, 0, 0);
        }
        v4f C0s = C0a + C0b, C1s = C1a + C1b;
        z10 = C0s[0] + b1r0;  P0 = C0s[1];
        z11 = C1s[0] + b1r1;  P1 = C1s[1];
    }
    __syncthreads();   // protect ubuf before loop overwrites

    const float dt = 0.01f, hdt = 0.005f, dt6 = 0.01f / 6.f;
    const float dtdt6 = dt * dt6, hdt2 = hdt * hdt, dthdt = dt * hdt;
    // quad's stage: aq (P coeff), bq (lagged-Y coeff); stage weights
    const float aq  = (quad == 0) ? 0.f : (quad == 3) ? dt : hdt;
    const float bq  = (quad == 2) ? hdt2 : (quad == 3) ? dthdt : 0.f;
    const float wsp = (quad == 0 || quad == 3) ? 1.f : 2.f;
    const float wsq = (quad == 3) ? 0.f : 1.f;

    // lagged Y1,Y2 per comp (step 0: 0 -> dz3 ~ hdt^2*Y1 ~ 2.5e-5, benign)
    float hY0 = 0.f, hY1v = 0.f;   // quad2 uses Y1, quad3 uses Y2: per-quad lag
    float S1p0 = 0.f, S23p0 = 0.f, S1p1 = 0.f, S23p1 = 0.f, cn = 99.f;

    #pragma unroll 1
    for (int n = 0; n < NSTEPS; ++n) {
        // ---- quad-assigned stage z (both comps), lagged Y in bq term ----
        float zA0 = z10 + aq * P0 - bq * hY0;
        float zA1 = z11 + aq * P1 - bq * hY1v;
        float e0 = __expf(2.f * zA0), e1 = __expf(2.f * zA1);
        float hh0 = 1.f - 2.f / (e0 + 1.f), hh1 = 1.f - 2.f / (e1 + 1.f);
        float u0 = (1.f - hh0 * hh0) * w2r0, u1 = (1.f - hh1 * hh1) * w2r1;
        ubuf[quad * US + c0] = (_Float16)u0;   // full-exec: row quad = stage
        ubuf[quad * US + c1] = (_Float16)u1;
        __syncthreads();

        // ---- ONE MFMA block: Y1..Y4 for both comps, all in-lane ----
        float Y10, Y20, Y30, Y40, Y11, Y21, Y31, Y41;
        {
            const _Float16* ab = ubuf + sel + 8 * quad;
            v4f C0a = {0.f,0.f,0.f,0.f}, C0b = {0.f,0.f,0.f,0.f};
            v4f C1a = {0.f,0.f,0.f,0.f}, C1b = {0.f,0.f,0.f,0.f};
            #pragma unroll
            for (int kk = 0; kk < 8; kk += 2) {
                v8h a0 = *(const v8h*)(ab + 32 * kk);
                v8h a1 = *(const v8h*)(ab + 32 * (kk + 1));
                MFMA_AV(C0a, a0, wM0[kk]);
                MFMA_AV(C1a, a0, wM1[kk]);
                MFMA_AV(C0b, a1, wM0[kk + 1]);
                MFMA_AV(C1b, a1, wM1[kk + 1]);
            }
            v4f C0s = C0a + C0b, C1s = C1a + C1b;
            Y10 = C0s[0]; Y20 = C0s[1]; Y30 = C0s[2]; Y40 = C0s[3];
            Y11 = C1s[0]; Y21 = C1s[1]; Y31 = C1s[2]; Y41 = C1s[3];
        }
        __syncthreads();   // all waves done reading before next-step writes

        // ---- step update (exact current Ys); refresh lagged Y ----
        z10 = z10 + dt * P0 - dtdt6 * (Y10 + Y20 + Y30);
        P0  = P0 - dt6 * (Y10 + 2.f * Y20 + 2.f * Y30 + Y40);
        z11 = z11 + dt * P1 - dtdt6 * (Y11 + Y21 + Y31);
        P1  = P1 - dt6 * (Y11 + 2.f * Y21 + 2.f * Y31 + Y41);
        hY0  = (quad == 3) ? Y20 : Y10;   // quad2 lags Y1, quad3 lags Y2
        hY1v = (quad == 3) ? Y21 : Y11;

        // ---- per-lane S partials (own stage's u, both comps) ----
        S1p0 += wsp * u0;  S23p0 += cn * (wsp * u0) + wsq * u0;
        S1p1 += wsp * u1;  S23p1 += cn * (wsp * u1) + wsq * u1;
        cn -= 1.f;
    }

    // ---- epilogue: reduce S over the 4 quads; rows {S1, S23} ----
    S1p0  += __shfl_xor(S1p0, 16, 64);   S1p0  += __shfl_xor(S1p0, 32, 64);
    S23p0 += __shfl_xor(S23p0, 16, 64);  S23p0 += __shfl_xor(S23p0, 32, 64);
    S1p1  += __shfl_xor(S1p1, 16, 64);   S1p1  += __shfl_xor(S1p1, 32, 64);
    S23p1 += __shfl_xor(S23p1, 16, 64);  S23p1 += __shfl_xor(S23p1, 32, 64);
    __syncthreads();
    if (quad == 0) {
        ubuf[c0] = (_Float16)S1p0;       ubuf[c1] = (_Float16)S1p1;
        ubuf[US + c0] = (_Float16)S23p0; ubuf[US + c1] = (_Float16)S23p1;
        ubuf[2 * US + c0] = (_Float16)0.f;  ubuf[2 * US + c1] = (_Float16)0.f;
        ubuf[3 * US + c0] = (_Float16)0.f;  ubuf[3 * US + c1] = (_Float16)0.f;
    }
    __syncthreads();
    // wBt[kk][j] = W[c][32kk+8quad+j] = wldsT[(32kk+8quad+j)*WS + c]
    v8h wBt0[8], wBt1[8];
    #pragma unroll
    for (int kk = 0; kk < 8; ++kk)
        #pragma unroll
        for (int j = 0; j < 8; ++j) {
            wBt0[kk][j] = wldsT[(32 * kk + 8 * quad + j) * WS + c0];
            wBt1[kk][j] = wldsT[(32 * kk + 8 * quad + j) * WS + c1];
        }
    float D10, D20, D11, D21;
    {
        const _Float16* ab = ubuf + sel + 8 * quad;
        v4f C0a = {0.f,0.f,0.f,0.f}, C0b = {0.f,0.f,0.f,0.f};
        v4f C1a = {0.f,0.f,0.f,0.f}, C1b = {0.f,0.f,0.f,0.f};
        #pragma unroll
        for (int kk = 0; kk < 8; kk += 2) {
            v8h a0 = *(const v8h*)(ab + 32 * kk);
            v8h a1 = *(const v8h*)(ab + 32 * (kk + 1));
            C0a = __builtin_amdgcn_mfma_f32_16x16x32_f16(a0, wBt0[kk], C0a, 0, 0, 0);
            C1a = __builtin_amdgcn_mfma_f32_16x16x32_f16(a0, wBt1[kk], C1a, 0, 0, 0);
            C0b = __builtin_amdgcn_mfma_f32_16x16x32_f16(a1, wBt0[kk + 1], C0b, 0, 0, 0);
            C1b = __builtin_amdgcn_mfma_f32_16x16x32_f16(a1, wBt1[kk + 1], C1b, 0, 0, 0);
        }
        v4f C0s = C0a + C0b, C1s = C1a + C1b;
        D10 = C0s[0];  D20 = C0s[1];
        D11 = C1s[0];  D21 = C1s[1];
    }
    const float dt6e = 0.01f / 6.f, dtdt6e = 0.01f * dt6e;
    float pT0 = p0o0 - dt6e * D10;
    float qT0 = q0o0 + 0.01f * (float)NSTEPS * p0o0 - dtdt6e * D20;
    float pT1 = p0o1 - dt6e * D11;
    float qT1 = q0o1 + 0.01f * (float)NSTEPS * p0o1 - dtdt6e * D21;

    if (quad == 0) {
        ((float2*)(out + (size_t)blk * 512))[c0] = make_float2(qT0, pT0);
        ((float2*)(out + (size_t)blk * 512))[c1] = make_float2(qT1, pT1);
    }
}

extern "C" void kernel_launch(void* const* d_in, const int* in_sizes, int n_in,
                              void* d_out, int out_size, void* d_ws, size_t ws_size,
                              hipStream_t stream) {
    const float* x0 = (const float*)d_in[0];
    const float* W1 = (const float*)d_in[1];
    const float* b1 = (const float*)d_in[2];
    const float* W2 = (const float*)d_in[3];
    // d_in[4] = b2: constant offset, no effect on the gradient/dynamics.
    float* out = (float*)d_out;
    hipLaunchKernelGGL(ham_kernel, dim3(256), dim3(512), 0, stream,
                       x0, W1, b1, W2, out);
}

// Round 24
// 138.381 us; speedup vs baseline: 1.7195x; 1.0157x over previous
//
#include <hip/hip_runtime.h>
#include <stdint.h>

// HamiltonianFlow: x [256, 8, 32, 2] (q,p); H = 0.5*sum(p^2) + MLP(q).
// dq/dt = p, dp/dt = -W u(z), z = W^T q + b1, u = (1-tanh^2(z)).*W2.
// 100 RK4 steps, z-space iteration with M = W^T W (R15-R23 verified):
//   z2 = z1+hdt*P; z3 = z1+hdt*P-hdt^2*Y1^; z4 = z1+dt*P-dt*hdt*Y2^
//   (Y1^,Y2^ = previous step's, R23-verified lag: dz ~ 2.5e-7, 100x below
//   the f16 u-rounding already dominating absmax)
//   z1' = z1+dt*P-dt*dt6*(Y1+Y2+Y3);  P' = P-dt6*(Y1+2Y2+2Y3+Y4)  [exact Ys]
// All 4 u's computed at step top -> 4 vectors packed in A rows m%4={0,1,2,3},
// ONE 16-MFMA block/wave/step yields Y1..Y4 in-lane (C[0..3]), both tiles.
//
// R24 = R23 + DOUBLE-BUFFERED ubuf -> ONE barrier/step (the dependency
// minimum). R23 paid 2 barriers: the second only protected MFMA-reads from
// next-step u-writes. With 2 alternating 4-row buffers (iter n: write buf
// n&1 -> barrier -> read buf n&1), a fast wave reaches iter-(n+2) writes of
// buf b only after barrier n+1, which every wave reaches only after its
// iter-n reads of buf b completed -> race-free with 1 barrier/iter.
// ubuf row stride US=272 f16 (544 B == 32 mod 128): 4 vector rows on 4 bank
// quarters, residual 2-way aliasing free (m136).
// Quad-split nonlinearity (R22): quad q computes stage q+1 for both comps
// (2 exp/lane/step); stage weights wsp={1,2,2,1}, wsq={1,1,1,0}; S partials
// reduced by shfl_xor(16)+shfl_xor(32) in the epilogue.
// 8 waves x 2 tiles (2/SIMD overlap), transposed W^T staging (contiguous
// b128 wF/aM), AGPR-direct wM ("a" constraint), M-build scr stride 20.
// Reconstruction (R15): sp=u1+2u2+2u3+u4, sq=u1+u2+u3; S1=sum sp_n,
// S23=sum (99-n)sp_n+sq_n; p_T=p0-dt6*W*S1, q_T=q0+dt*100*p0-dt*dt6*W*S23.
// FULL unroll on every reg-array access (R4: dynamic index => scratch).
// Numerics: f16 storage (W, M, u, S), fp32 MFMA accum + fp32 z1/P state.

typedef _Float16 v8h __attribute__((ext_vector_type(8)));
typedef float v4f __attribute__((ext_vector_type(4)));

#define NSTEPS 100
#define WS 264    // wldsT row stride (f16): row = one W-COLUMN, 16B-aligned
#define US 272    // ubuf row stride, f16 (544 B == 32 mod 128: 4-way split)

// D(+=C) in VGPRs, A (packed-vector frag) in VGPRs, B (M-frag) from AGPRs.
#define MFMA_AV(C, A, B) \
    asm("v_mfma_f32_16x16x32_f16 %0, %1, %2, %0" : "+v"(C) : "v"(A), "a"(B))

__global__ __launch_bounds__(512, 2)
void ham_kernel(const float* __restrict__ x0, const float* __restrict__ W1,
                const float* __restrict__ b1, const float* __restrict__ W2,
                float* __restrict__ out)
{
    __shared__ __align__(16)  _Float16 wldsT[256 * WS];  // 135168 B: W^T (f16)
    __shared__ __align__(16)  float    mscr[8 * 640];    // 20480 B: M scratch
    __shared__ __align__(128) _Float16 ubuf[8 * US];     // 4352 B: 2 x 4 rows

    const int t = threadIdx.x;
    const int w = t >> 6;          // wave 0..7: owns tiles {2w, 2w+1}
    const int l = t & 63;
    const int quad = l >> 4;       // K-subgroup / stage slot (stage quad+1)
    const int s = l & 15;          // owned column / A-row
    const int c0 = 32 * w + s;          // comp, tile 2w
    const int c1 = 32 * w + 16 + s;     // comp, tile 2w+1
    const int blk = blockIdx.x;
    const int sel = (s & 3) * US;  // A-row m%4 = r -> vector r

    // ---- stage W^T -> LDS f16: wldsT[c][r] = W[r][c] ----
    {
        const int c = t & 255;
        const int rbase = (t >> 8) * 128;
        #pragma unroll 1
        for (int r0 = 0; r0 < 128; r0 += 8) {
            v8h h;
            #pragma unroll
            for (int j = 0; j < 8; ++j)
                h[j] = (_Float16)W1[(rbase + r0 + j) * 256 + c];
            *(v8h*)(wldsT + c * WS + rbase + r0) = h;   // b128, one-time
        }
    }
    __syncthreads();

    // ---- wF: own-column W^T frags (B-op), contiguous b128 from wldsT ----
    v8h wF0[8], wF1[8];
    #pragma unroll
    for (int kk = 0; kk < 8; ++kk) {
        wF0[kk] = *(const v8h*)(wldsT + c0 * WS + 32 * kk + 8 * quad);
        wF1[kk] = *(const v8h*)(wldsT + c1 * WS + 32 * kk + 8 * quad);
    }

    // ---- build M = W^T W column-block frags wM0/wM1 (B-op: M[k][c]) ----
    v8h wM0[8], wM1[8];
    float* scr0 = mscr + w * 640;
    float* scr1 = scr0 + 320;
    #pragma unroll
    for (int kb = 0; kb < 16; ++kb) {
        v8h aM[8];   // A[m=s][k=8quad+j] = wldsT[(16kb+s)*WS + 32kk+8quad+j]
        #pragma unroll
        for (int kk = 0; kk < 8; ++kk)
            aM[kk] = *(const v8h*)(wldsT + (16 * kb + s) * WS
                                          + 32 * kk + 8 * quad);
        v4f D0 = {0.f,0.f,0.f,0.f}, D1 = {0.f,0.f,0.f,0.f};
        #pragma unroll
        for (int kk = 0; kk < 8; ++kk) {
            D0 = __builtin_amdgcn_mfma_f32_16x16x32_f16(aM[kk], wF0[kk], D0, 0, 0, 0);
            D1 = __builtin_amdgcn_mfma_f32_16x16x32_f16(aM[kk], wF1[kk], D1, 0, 0, 0);
        }
        *(v4f*)(scr0 + s * 20 + 4 * quad) = D0;
        *(v4f*)(scr1 + s * 20 + 4 * quad) = D1;
        asm volatile("s_waitcnt lgkmcnt(0)" ::: "memory");  // in-wave x-lane
        if ((quad >> 1) == (kb & 1)) {
            #pragma unroll
            for (int j = 0; j < 8; ++j) {
                wM0[kb >> 1][j] = (_Float16)scr0[s * 20 + 8 * (quad & 1) + j];
                wM1[kb >> 1][j] = (_Float16)scr1[s * 20 + 8 * (quad & 1) + j];
            }
        }
        asm volatile("s_waitcnt lgkmcnt(0)" ::: "memory");
    }

    const float b1r0 = b1[c0], b1r1 = b1[c1];
    const float w2r0 = W2[c0], w2r1 = W2[c1];
    float2 qp0 = ((const float2*)(x0 + (size_t)blk * 512))[c0];
    float2 qp1 = ((const float2*)(x0 + (size_t)blk * 512))[c1];
    const float q0o0 = qp0.x, p0o0 = qp0.y;
    const float q0o1 = qp1.x, p0o1 = qp1.y;

    // ---- prologue: buf0 rows {q0, p0, 0, 0} -> z1 (C[0]), P (C[1]) ----
    if (quad == 0) {
        ubuf[c0] = (_Float16)q0o0;  ubuf[c1] = (_Float16)q0o1;
        ubuf[US + c0] = (_Float16)p0o0;  ubuf[US + c1] = (_Float16)p0o1;
        ubuf[2 * US + c0] = (_Float16)0.f;  ubuf[2 * US + c1] = (_Float16)0.f;
        ubuf[3 * US + c0] = (_Float16)0.f;  ubuf[3 * US + c1] = (_Float16)0.f;
    }
    __syncthreads();
    float z10, P0, z11, P1;
    {
        const _Float16* ab = ubuf + sel + 8 * quad;
        v4f C0a = {0.f,0.f,0.f,0.f}, C0b = {0.f,0.f,0.f,0.f};
        v4f C1a = {0.f,0.f,0.f,0.f}, C1b = {0.f,0.f,0.f,0.f};
        #pragma unroll
        for (int kk = 0; kk < 8; kk += 2) {
            v8h a0 = *(const v8h*)(ab + 32 * kk);
            v8h a1 = *(const v8h*)(ab + 32 * (kk + 1));
            C0a = __builtin_amdgcn_mfma_f32_16x16x32_f16(a0, wF0[kk], C0a, 0, 0, 0);
            C1a = __builtin_amdgcn_mfma_f32_16x16x32_f16(a0, wF1[kk], C1a, 0, 0, 0);
            C0b = __builtin_amdgcn_mfma_f32_16x16x32_f16(a1, wF0[kk + 1], C0b, 0, 0, 0);
            C1b = __builtin_amdgcn_mfma_f32_16x16x32_f16(a1, wF1[kk + 1], C1b, 0, 0, 0);
        }
        v4f C0s = C0a + C0b, C1s = C1a + C1b;
        z10 = C0s[0] + b1r0;  P0 = C0s[1];
        z11 = C1s[0] + b1r1;  P1 = C1s[1];
    }
    __syncthreads();   // prologue reads done before iter-0 overwrites buf0

    const float dt = 0.01f, hdt = 0.005f, dt6 = 0.01f / 6.f;
    const float dtdt6 = dt * dt6, hdt2 = hdt * hdt, dthdt = dt * hdt;
    // quad's stage: aq (P coeff), bq (lagged-Y coeff); stage weights
    const float aq  = (quad == 0) ? 0.f : (quad == 3) ? dt : hdt;
    const float bq  = (quad == 2) ? hdt2 : (quad == 3) ? dthdt : 0.f;
    const float wsp = (quad == 0 || quad == 3) ? 1.f : 2.f;
    const float wsq = (quad == 3) ? 0.f : 1.f;

    // lagged Y (step 0: 0 -> dz3 ~ hdt^2*Y1 ~ 2.5e-5, benign)
    float hY0 = 0.f, hY1v = 0.f;   // quad2 lags Y1, quad3 lags Y2
    float S1p0 = 0.f, S23p0 = 0.f, S1p1 = 0.f, S23p1 = 0.f, cn = 99.f;

    #pragma unroll 1
    for (int n = 0; n < NSTEPS; ++n) {
        const int bo = (n & 1) * (4 * US);   // double-buffer offset

        // ---- quad-assigned stage z (both comps), lagged Y in bq term ----
        float zA0 = z10 + aq * P0 - bq * hY0;
        float zA1 = z11 + aq * P1 - bq * hY1v;
        float e0 = __expf(2.f * zA0), e1 = __expf(2.f * zA1);
        float hh0 = 1.f - 2.f / (e0 + 1.f), hh1 = 1.f - 2.f / (e1 + 1.f);
        float u0 = (1.f - hh0 * hh0) * w2r0, u1 = (1.f - hh1 * hh1) * w2r1;
        ubuf[bo + quad * US + c0] = (_Float16)u0;   // full-exec writes
        ubuf[bo + quad * US + c1] = (_Float16)u1;
        __syncthreads();   // the ONLY barrier per step

        // ---- ONE MFMA block: Y1..Y4 for both comps, all in-lane ----
        float Y10, Y20, Y30, Y40, Y11, Y21, Y31, Y41;
        {
            const _Float16* ab = ubuf + bo + sel + 8 * quad;
            v4f C0a = {0.f,0.f,0.f,0.f}, C0b = {0.f,0.f,0.f,0.f};
            v4f C1a = {0.f,0.f,0.f,0.f}, C1b = {0.f,0.f,0.f,0.f};
            #pragma unroll
            for (int kk = 0; kk < 8; kk += 2) {
                v8h a0 = *(const v8h*)(ab + 32 * kk);
                v8h a1 = *(const v8h*)(ab + 32 * (kk + 1));
                MFMA_AV(C0a, a0, wM0[kk]);
                MFMA_AV(C1a, a0, wM1[kk]);
                MFMA_AV(C0b, a1, wM0[kk + 1]);
                MFMA_AV(C1b, a1, wM1[kk + 1]);
            }
            v4f C0s = C0a + C0b, C1s = C1a + C1b;
            Y10 = C0s[0]; Y20 = C0s[1]; Y30 = C0s[2]; Y40 = C0s[3];
            Y11 = C1s[0]; Y21 = C1s[1]; Y31 = C1s[2]; Y41 = C1s[3];
        }
        // no second barrier: next iter writes the OTHER buffer; any wave
        // reaching those writes has passed this iter's barrier, which
        // implies all waves finished the previous buffer's reads.

        // ---- step update (exact current Ys); refresh lagged Y ----
        z10 = z10 + dt * P0 - dtdt6 * (Y10 + Y20 + Y30);
        P0  = P0 - dt6 * (Y10 + 2.f * Y20 + 2.f * Y30 + Y40);
        z11 = z11 + dt * P1 - dtdt6 * (Y11 + Y21 + Y31);
        P1  = P1 - dt6 * (Y11 + 2.f * Y21 + 2.f * Y31 + Y41);
        hY0  = (quad == 3) ? Y20 : Y10;
        hY1v = (quad == 3) ? Y21 : Y11;

        // ---- per-lane S partials (own stage's u, both comps) ----
        S1p0 += wsp * u0;  S23p0 += cn * (wsp * u0) + wsq * u0;
        S1p1 += wsp * u1;  S23p1 += cn * (wsp * u1) + wsq * u1;
        cn -= 1.f;
    }

    // ---- epilogue: reduce S over the 4 quads; buf0 rows {S1, S23, 0, 0} ----
    S1p0  += __shfl_xor(S1p0, 16, 64);   S1p0  += __shfl_xor(S1p0, 32, 64);
    S23p0 += __shfl_xor(S23p0, 16, 64);  S23p0 += __shfl_xor(S23p0, 32, 64);
    S1p1  += __shfl_xor(S1p1, 16, 64);   S1p1  += __shfl_xor(S1p1, 32, 64);
    S23p1 += __shfl_xor(S23p1, 16, 64);  S23p1 += __shfl_xor(S23p1, 32, 64);
    __syncthreads();
    if (quad == 0) {
        ubuf[c0] = (_Float16)S1p0;       ubuf[c1] = (_Float16)S1p1;
        ubuf[US + c0] = (_Float16)S23p0; ubuf[US + c1] = (_Float16)S23p1;
        ubuf[2 * US + c0] = (_Float16)0.f;  ubuf[2 * US + c1] = (_Float16)0.f;
        ubuf[3 * US + c0] = (_Float16)0.f;  ubuf[3 * US + c1] = (_Float16)0.f;
    }
    __syncthreads();
    // wBt[kk][j] = W[c][32kk+8quad+j] = wldsT[(32kk+8quad+j)*WS + c]
    v8h wBt0[8], wBt1[8];
    #pragma unroll
    for (int kk = 0; kk < 8; ++kk)
        #pragma unroll
        for (int j = 0; j < 8; ++j) {
            wBt0[kk][j] = wldsT[(32 * kk + 8 * quad + j) * WS + c0];
            wBt1[kk][j] = wldsT[(32 * kk + 8 * quad + j) * WS + c1];
        }
    float D10, D20, D11, D21;
    {
        const _Float16* ab = ubuf + sel + 8 * quad;
        v4f C0a = {0.f,0.f,0.f,0.f}, C0b = {0.f,0.f,0.f,0.f};
        v4f C1a = {0.f,0.f,0.f,0.f}, C1b = {0.f,0.f,0.f,0.f};
        #pragma unroll
        for (int kk = 0; kk < 8; kk += 2) {
            v8h a0 = *(const v8h*)(ab + 32 * kk);
            v8h a1 = *(const v8h*)(ab + 32 * (kk + 1));
            C0a = __builtin_amdgcn_mfma_f32_16x16x32_f16(a0, wBt0[kk], C0a, 0, 0, 0);
            C1a = __builtin_amdgcn_mfma_f32_16x16x32_f16(a0, wBt1[kk], C1a, 0, 0, 0);
            C0b = __builtin_amdgcn_mfma_f32_16x16x32_f16(a1, wBt0[kk + 1], C0b, 0, 0, 0);
            C1b = __builtin_amdgcn_mfma_f32_16x16x32_f16(a1, wBt1[kk + 1], C1b, 0, 0, 0);
        }
        v4f C0s = C0a + C0b, C1s = C1a + C1b;
        D10 = C0s[0];  D20 = C0s[1];
        D11 = C1s[0];  D21 = C1s[1];
    }
    const float dt6e = 0.01f / 6.f, dtdt6e = 0.01f * dt6e;
    float pT0 = p0o0 - dt6e * D10;
    float qT0 = q0o0 + 0.01f * (float)NSTEPS * p0o0 - dtdt6e * D20;
    float pT1 = p0o1 - dt6e * D11;
    float qT1 = q0o1 + 0.01f * (float)NSTEPS * p0o1 - dtdt6e * D21;

    if (quad == 0) {
        ((float2*)(out + (size_t)blk * 512))[c0] = make_float2(qT0, pT0);
        ((float2*)(out + (size_t)blk * 512))[c1] = make_float2(qT1, pT1);
    }
}

extern "C" void kernel_launch(void* const* d_in, const int* in_sizes, int n_in,
                              void* d_out, int out_size, void* d_ws, size_t ws_size,
                              hipStream_t stream) {
    const float* x0 = (const float*)d_in[0];
    const float* W1 = (const float*)d_in[1];
    const float* b1 = (const float*)d_in[2];
    const float* W2 = (const float*)d_in[3];
    // d_in[4] = b2: constant offset, no effect on the gradient/dynamics.
    float* out = (float*)d_out;
    hipLaunchKernelGGL(ham_kernel, dim3(256), dim3(512), 0, stream,
                       x0, W1, b1, W2, out);
}